// Round 13
// baseline (2500.354 us; speedup 1.0000x reference)
//
#include <hip/hip_runtime.h>
#include <math.h>

#define THREADS 256

// Dims: B=8, C(seq)=10, F(dim)=48, H=W=64, HEADS=8, hd=6, MLP=192
// Stage2: NI=80 images, CH=96, PW=384, OUTF=48

// transposed shortcut weights [96][48], filled by kt_transpose each launch
__device__ float g_scwT[96 * 48];

// ---------------- Kernel T: transpose sc_w (48x96 -> 96x48), one-off ----------------
__global__ void kt_transpose(const float* __restrict__ sc_w) {
    int i = threadIdx.x + blockIdx.x * 256;
    if (i < 48 * 96) {
        int o = i / 96, k = i % 96;
        g_scwT[k * 48 + o] = sc_w[o * 96 + k];
    }
}

// ---------------- Kernel A (v5): ka2 weight path + 4 phase-locked waves/block ----------------
// Per-wave code identical to ka2 (880us verified: rolled loops, original weight
// layout, lane=token, shfl attention). NEW: 4 waves per block (24 sequences),
// __syncthreads() after each h-phase and cc-phase. All 4 waves walk the SAME
// 3.5-9KB weight chunk in a tight window -> each K$/L2 line fetched once,
// consumed 4x (s_load miss latency was the 60% stall). Barriers are uniform
// control flow (fixed trip counts; act-masking affects only loads/stores).
// LDS 50KB -> 3 blocks/CU = 12 waves/CU (same occupancy as ka2).
#define LKS 49

__global__ __launch_bounds__(256, 3) void ka5_transformer(
    const float* __restrict__ x,
    const float* __restrict__ qkv_w, const float* __restrict__ qkv_b,
    const float* __restrict__ proj_w, const float* __restrict__ proj_b,
    const float* __restrict__ ff1_w, const float* __restrict__ ff1_b,
    const float* __restrict__ ff2_w, const float* __restrict__ ff2_b,
    float* __restrict__ t_out)
{
    __shared__ float tl[256 * LKS];    // per-thread token row (48 data + 1 pad)
    const int tid  = threadIdx.x;
    const int lane = tid & 63;
    const int w    = tid >> 6;         // wave id 0..3

    // bijective XCD swizzle (grid not divisible by 8): chunked assignment
    const int nb  = gridDim.x;
    const int q8  = nb >> 3, r8 = nb & 7;
    const int xcd = blockIdx.x & 7, idx = blockIdx.x >> 3;
    const int wg  = (xcd < r8) ? xcd * (q8 + 1) + idx
                               : r8 * (q8 + 1) + (xcd - r8) * q8 + idx;

    const int s = lane / 10;
    const int c = lane - s * 10;                 // seq position 0..9
    const int g = wg * 24 + w * 6 + s;           // global pixel (sequence) id
    const bool act = (lane < 60) && (g < 32768);
    const int b   = g >> 12;                     // batch image
    const int pix = g & 4095;

    float* tr = tl + tid * LKS;

    if (act) {
        const float* xp = x + ((size_t)(b * 480 + c * 48)) * 4096 + pix;
        #pragma unroll
        for (int f = 0; f < 48; ++f) tr[f] = xp[(size_t)f * 4096];
    } else {
        #pragma unroll
        for (int f = 0; f < 48; ++f) tr[f] = 0.f;
    }

    const float scale = 0.4082482904638631f;     // 6^-0.5
    const float NEG = -3.4e38f;

    for (int l = 0; l < 2; ++l) {
        const float* qw  = qkv_w + l * 6912;
        const float* qb  = qkv_b + l * 144;
        const float* pw  = proj_w + l * 2304;
        const float* pb  = proj_b + l * 48;
        const float* f1w = ff1_w + l * 9216;
        const float* f1b = ff1_b + l * 192;
        const float* f2w = ff2_w + l * 9216;
        const float* f2b = ff2_b + l * 48;

        float pacc[48];
        #pragma unroll
        for (int o = 0; o < 48; ++o) pacc[o] = 0.f;

        for (int h = 0; h < 8; ++h) {
            float qa[6], ka[6], va[6];
            #pragma unroll
            for (int d = 0; d < 6; ++d) { qa[d] = 0.f; ka[d] = 0.f; va[d] = 0.f; }

            for (int k = 0; k < 48; ++k) {
                const float tk = tr[k];
                const float* wr = qw + k * 144 + h * 6;
                #pragma unroll
                for (int d = 0; d < 6; ++d) {
                    qa[d] += tk * wr[d];
                    ka[d] += tk * wr[48 + d];
                    va[d] += tk * wr[96 + d];
                }
            }
            #pragma unroll
            for (int d = 0; d < 6; ++d) {
                qa[d] += qb[h * 6 + d];
                ka[d] += qb[48 + h * 6 + d];
                va[d] += qb[96 + h * 6 + d];
            }

            float qm[6], qp[6], vm[6], vp[6];
            #pragma unroll
            for (int d = 0; d < 6; ++d) {
                qm[d] = __shfl_up(qa[d], 1);
                qp[d] = __shfl_down(qa[d], 1);
                vm[d] = __shfl_up(va[d], 1);
                vp[d] = __shfl_down(va[d], 1);
            }
            float s0 = 0.f, sm = 0.f, sp = 0.f;
            #pragma unroll
            for (int d = 0; d < 6; ++d) {
                s0 += ka[d] * qa[d];
                sm += ka[d] * qm[d];
                sp += ka[d] * qp[d];
            }
            s0 *= scale; sm *= scale; sp *= scale;
            if (c == 0) sm = NEG;
            if (c == 9) sp = NEG;
            const float mx = fmaxf(s0, fmaxf(sm, sp));
            const float em = expf(sm - mx), e0 = expf(s0 - mx), ep = expf(sp - mx);
            const float inv = 1.0f / (em + e0 + ep);

            #pragma unroll
            for (int d = 0; d < 6; ++d) {
                const float ov = (em * vm[d] + e0 * va[d] + ep * vp[d]) * inv;
                const float* wr = pw + (h * 6 + d) * 48;
                #pragma unroll
                for (int o = 0; o < 48; ++o) pacc[o] += ov * wr[o];
            }
            __syncthreads();   // phase-lock the 4 waves on the h-chunk
        }
        #pragma unroll
        for (int f = 0; f < 48; ++f) tr[f] += pacc[f] + pb[f];

        float facc[48];
        #pragma unroll
        for (int o = 0; o < 48; ++o) facc[o] = 0.f;

        for (int cc = 0; cc < 8; ++cc) {
            float ha[24];
            #pragma unroll
            for (int j = 0; j < 24; ++j) ha[j] = 0.f;

            for (int k = 0; k < 48; ++k) {
                const float tk = tr[k];
                const float* wr = f1w + k * 192 + cc * 24;
                #pragma unroll
                for (int j = 0; j < 24; ++j) ha[j] += tk * wr[j];
            }
            #pragma unroll
            for (int j = 0; j < 24; ++j) {
                float v = ha[j] + f1b[cc * 24 + j];
                ha[j] = 0.5f * v * (1.f + erff(v * 0.70710678118654752f));
            }
            #pragma unroll
            for (int j = 0; j < 24; ++j) {
                const float hj = ha[j];
                const float* wr = f2w + (cc * 24 + j) * 48;
                #pragma unroll
                for (int o = 0; o < 48; ++o) facc[o] += hj * wr[o];
            }
            __syncthreads();   // phase-lock the 4 waves on the cc-chunk
        }
        #pragma unroll
        for (int f = 0; f < 48; ++f) tr[f] += facc[f] + f2b[f];
    }

    if (act) {
        float* dst = t_out + (size_t)g * 480 + c * 48;
        #pragma unroll
        for (int u = 0; u < 12; ++u) {
            float4 v;
            v.x = tr[u * 4]; v.y = tr[u * 4 + 1];
            v.z = tr[u * 4 + 2]; v.w = tr[u * 4 + 3];
            *(float4*)(dst + u * 4) = v;
        }
    }
}

// ---------------- Kernel B: depthwise 3x3 conv (SAME) + transpose to pixel-major ----------------
__global__ __launch_bounds__(THREADS) void kb_conv(
    const float* __restrict__ x, const float* __restrict__ t_in,
    const float* __restrict__ dw_w, const float* __restrict__ dw_b,
    float* __restrict__ z0)
{
    __shared__ float ct[100 * 97];     // 10x10 halo tile x 96 ch, stride 97 (bank pad)
    const int tid = threadIdx.x;
    const int blk = blockIdx.x;
    const int n = blk >> 6;            // image (b*10+c)
    const int tile = blk & 63;
    const int th0 = (tile >> 3) << 3;
    const int tw0 = (tile & 7) << 3;
    const int b = n / 10, c = n % 10;

    for (int idx = tid; idx < 4800; idx += THREADS) {
        int f = idx / 100, p = idx % 100;
        int py = p / 10, px = p % 10;
        int gh = th0 + py - 1, gw = tw0 + px - 1;
        float v = 0.f;
        if ((unsigned)gh < 64u && (unsigned)gw < 64u)
            v = x[((size_t)n * 48 + f) * 4096 + gh * 64 + gw];
        ct[p * 97 + f] = v;
    }
    for (int idx = tid; idx < 4800; idx += THREADS) {
        int p = idx / 48, f = idx % 48;
        int py = p / 10, px = p % 10;
        int gh = th0 + py - 1, gw = tw0 + px - 1;
        float v = 0.f;
        if ((unsigned)gh < 64u && (unsigned)gw < 64u)
            v = t_in[(size_t)(b * 4096 + gh * 64 + gw) * 480 + c * 48 + f];
        ct[p * 97 + 48 + f] = v;
    }
    __syncthreads();

    #pragma unroll 4
    for (int it = 0; it < 24; ++it) {
        int oidx = tid + it * THREADS;   // 24*256 == 6144 == 64px * 96ch
        int pxl = oidx / 96, ch = oidx % 96;
        int py = pxl >> 3, pxx = pxl & 7;
        const float* wp = dw_w + ch * 9;
        float acc = dw_b[ch];
        #pragma unroll
        for (int dy = 0; dy < 3; ++dy)
            #pragma unroll
            for (int dx = 0; dx < 3; ++dx)
                acc += ct[((py + dy) * 10 + pxx + dx) * 97 + ch] * wp[dy * 3 + dx];
        z0[((size_t)n * 4096 + (th0 + py) * 64 + (tw0 + pxx)) * 96 + ch] = acc;
    }
}

// ---------------- Kernel C (v8, round-10 verified): lane = pixel, wave = j-slice ----------------
#define PBS 52

__global__ __launch_bounds__(THREADS, 4) void kc8_mlp(
    const float* __restrict__ x, const float* __restrict__ t_in,
    const float* __restrict__ z0,
    const float* __restrict__ ln_g, const float* __restrict__ ln_b,
    const float* __restrict__ pw1_w, const float* __restrict__ pw1_b,
    const float* __restrict__ pw2_w, const float* __restrict__ pw2_b,
    const float* __restrict__ sc_b,
    float* __restrict__ out)
{
    __shared__ float smem[3 * 64 * PBS];  // 9984 floats = 39.9KB union
    float* zb   = smem;                   // phase 1: z rows (64 x stride 100 = 6400)
    float* pbuf = smem;                   // phase 2: partials (3 x 64 x PBS)
    const int tid  = threadIdx.x;
    const int lane = tid & 63;
    const int w    = __builtin_amdgcn_readfirstlane(tid >> 6);  // SGPR wave id
    const int blk  = blockIdx.x;      // 5120
    const int n    = blk >> 6;        // image 0..79
    const int hw0  = (blk & 63) << 6; // 64-pixel run
    const size_t pixbase = (size_t)n * 4096 + hw0;

    // ---- stage z0 (contiguous 6144 floats) ----
    for (int idx = tid; idx < 1536; idx += THREADS) {
        float4 v = *(const float4*)(z0 + pixbase * 96 + (size_t)idx * 4);
        int p = idx / 24, c0 = (idx % 24) * 4;
        *(float4*)(&zb[p * 100 + c0]) = v;
    }
    __syncthreads();

    // ---- LayerNorm in place: one lane per pixel ----
    if (tid < 64) {
        float* r = zb + tid * 100;
        float mu = 0.f;
        #pragma unroll
        for (int k = 0; k < 96; ++k) mu += r[k];
        mu *= (1.f / 96.f);
        float var = 0.f;
        #pragma unroll
        for (int k = 0; k < 96; ++k) { float d = r[k] - mu; var += d * d; }
        var *= (1.f / 96.f);
        float rs = rsqrtf(var + 1e-6f);
        #pragma unroll
        for (int k = 0; k < 96; ++k) r[k] = (r[k] - mu) * rs * ln_g[k] + ln_b[k];
    }
    __syncthreads();

    // ---- per-wave partial: j in [96w, 96w+96), 4 sub-chunks of 24 ----
    float facc[48];
    #pragma unroll
    for (int o = 0; o < 48; ++o) facc[o] = (w == 0) ? pw2_b[o] : 0.f;

    const int jbase = w * 96;
    for (int sc4 = 0; sc4 < 4; ++sc4) {
        const int j0 = jbase + sc4 * 24;    // SGPR (w uniform, sc4 loop counter)
        float ha[24];
        #pragma unroll
        for (int j = 0; j < 24; ++j) ha[j] = 0.f;

        for (int k0 = 0; k0 < 96; k0 += 4) {
            float4 zv = *(const float4*)(&zb[lane * 100 + k0]);   // ds_read_b128
            {
                const float e = zv.x;
                const float* wr = pw1_w + (k0 + 0) * 384 + j0;    // s_load
                #pragma unroll
                for (int j = 0; j < 24; ++j) ha[j] += e * wr[j];
            }
            {
                const float e = zv.y;
                const float* wr = pw1_w + (k0 + 1) * 384 + j0;
                #pragma unroll
                for (int j = 0; j < 24; ++j) ha[j] += e * wr[j];
            }
            {
                const float e = zv.z;
                const float* wr = pw1_w + (k0 + 2) * 384 + j0;
                #pragma unroll
                for (int j = 0; j < 24; ++j) ha[j] += e * wr[j];
            }
            {
                const float e = zv.w;
                const float* wr = pw1_w + (k0 + 3) * 384 + j0;
                #pragma unroll
                for (int j = 0; j < 24; ++j) ha[j] += e * wr[j];
            }
        }
        #pragma unroll
        for (int j = 0; j < 24; ++j) {
            float v = ha[j] + pw1_b[j0 + j];
            ha[j] = 0.5f * v * (1.f + erff(v * 0.70710678118654752f));
        }
        #pragma unroll
        for (int j = 0; j < 24; ++j) {
            const float hj = ha[j];
            const float* wr = pw2_w + (j0 + j) * 48;              // s_load
            #pragma unroll
            for (int o = 0; o < 48; ++o) facc[o] += hj * wr[o];
        }
    }

    // ---- shortcut slice: wave w handles cat k in [24w, 24w+24) ----
    if (w < 2) {
        // x half (planar): k = 24w + i
        const float* xp = x + ((size_t)(n * 48 + w * 24)) * 4096 + hw0 + lane;
        #pragma unroll
        for (int i = 0; i < 24; ++i) {
            const float e = xp[(size_t)i * 4096];
            const float* wr = g_scwT + (w * 24 + i) * 48;         // s_load
            #pragma unroll
            for (int o = 0; o < 48; ++o) facc[o] += e * wr[o];
        }
    } else {
        // t half (pixel-major): k = 48 + 24(w-2) + u
        const float* tp = t_in + ((size_t)((n / 10) * 4096 + hw0 + lane)) * 480
                        + (n % 10) * 48 + (w - 2) * 24;
        #pragma unroll
        for (int u = 0; u < 6; ++u) {
            float4 v = *(const float4*)(tp + u * 4);
            const int kb = 48 + (w - 2) * 24 + u * 4;
            const float* w0p = g_scwT + (kb + 0) * 48;
            const float* w1p = g_scwT + (kb + 1) * 48;
            const float* w2p = g_scwT + (kb + 2) * 48;
            const float* w3p = g_scwT + (kb + 3) * 48;
            #pragma unroll
            for (int o = 0; o < 48; ++o) facc[o] += v.x * w0p[o];
            #pragma unroll
            for (int o = 0; o < 48; ++o) facc[o] += v.y * w1p[o];
            #pragma unroll
            for (int o = 0; o < 48; ++o) facc[o] += v.z * w2p[o];
            #pragma unroll
            for (int o = 0; o < 48; ++o) facc[o] += v.w * w3p[o];
        }
    }

    // ---- reduce partials (pbuf aliases zb: barrier before overwrite) ----
    __syncthreads();
    if (w > 0) {
        float* pb = pbuf + (w - 1) * (64 * PBS) + lane * PBS;
        #pragma unroll
        for (int o = 0; o < 48; ++o) pb[o] = facc[o];
    }
    __syncthreads();
    if (w == 0) {
        const float* p1 = pbuf + lane * PBS;
        const float* p2 = pbuf + (64 * PBS) + lane * PBS;
        const float* p3 = pbuf + 2 * (64 * PBS) + lane * PBS;
        #pragma unroll
        for (int o = 0; o < 48; ++o) facc[o] += p1[o];
        #pragma unroll
        for (int o = 0; o < 48; ++o) facc[o] += p2[o];
        #pragma unroll
        for (int o = 0; o < 48; ++o) facc[o] += p3[o];

        float* op = out + (size_t)n * 48 * 4096 + hw0 + lane;
        #pragma unroll
        for (int f = 0; f < 48; ++f)
            op[(size_t)f * 4096] = facc[f] + sc_b[f];
    }
}

extern "C" void kernel_launch(void* const* d_in, const int* in_sizes, int n_in,
                              void* d_out, int out_size, void* d_ws, size_t ws_size,
                              hipStream_t stream) {
    const float* x      = (const float*)d_in[0];
    const float* qkv_w  = (const float*)d_in[1];
    const float* qkv_b  = (const float*)d_in[2];
    const float* proj_w = (const float*)d_in[3];
    const float* proj_b = (const float*)d_in[4];
    const float* ff1_w  = (const float*)d_in[5];
    const float* ff1_b  = (const float*)d_in[6];
    const float* ff2_w  = (const float*)d_in[7];
    const float* ff2_b  = (const float*)d_in[8];
    const float* dw_w   = (const float*)d_in[9];
    const float* dw_b   = (const float*)d_in[10];
    const float* ln_g   = (const float*)d_in[11];
    const float* ln_b   = (const float*)d_in[12];
    const float* pw1_w  = (const float*)d_in[13];
    const float* pw1_b  = (const float*)d_in[14];
    const float* pw2_w  = (const float*)d_in[15];
    const float* pw2_b  = (const float*)d_in[16];
    const float* sc_w   = (const float*)d_in[17];
    const float* sc_b   = (const float*)d_in[18];
    float* out = (float*)d_out;

    // workspace: t_final (B*H*W,10,48) = 15,728,640 f ; z0 (80*4096,96) = 31,457,280 f
    float* t_out = (float*)d_ws;
    float* z0    = t_out + 15728640ull;

    kt_transpose<<<18, 256, 0, stream>>>(sc_w);
    // 32768 sequences, 24 per 4-wave block
    ka5_transformer<<<1366, 256, 0, stream>>>(x, qkv_w, qkv_b, proj_w, proj_b,
                                              ff1_w, ff1_b, ff2_w, ff2_b, t_out);
    kb_conv<<<5120, THREADS, 0, stream>>>(x, t_out, dw_w, dw_b, z0);
    kc8_mlp<<<5120, THREADS, 0, stream>>>(x, t_out, z0, ln_g, ln_b,
                                          pw1_w, pw1_b, pw2_w, pw2_b, sc_b, out);
}

// Round 14
// 1942.092 us; speedup vs baseline: 1.2875x; 1.2875x over previous
//
#include <hip/hip_runtime.h>
#include <math.h>

#define THREADS 256

// Dims: B=8, C(seq)=10, F(dim)=48, H=W=64, HEADS=8, hd=6, MLP=192
// Stage2: NI=80 images, CH=96, PW=384, OUTF=48

// transposed shortcut weights [96][48], filled by kt_transpose each launch
__device__ float g_scwT[96 * 48];

// ---------------- Kernel T: transpose sc_w (48x96 -> 96x48), one-off ----------------
__global__ void kt_transpose(const float* __restrict__ sc_w) {
    int i = threadIdx.x + blockIdx.x * 256;
    if (i < 48 * 96) {
        int o = i / 96, k = i % 96;
        g_scwT[k * 48 + o] = sc_w[o * 96 + k];
    }
}

// ---------------- Kernel A (v6): ka2 + lgkmcnt-stream separation ----------------
// ka2 (880us verified) stalls because tr[k] ds_reads interleave with weight
// s_loads: SMEM and DS share lgkmcnt and SMEM returns out-of-order, so every
// ds_read use forces lgkmcnt(0), draining the scalar prefetch queue (48
// drains per GEMV). v6 hoists t reads as 4x ds_read_b128 per 16-k block
// (3 drains per GEMV); the 16-step body is pure s_load+FMA. FMA order
// unchanged (k ascending) -> identical numerics.
#define LKS 49

#define QKV_STEP(TK, ROW) { \
    const float* wr_ = wb + (ROW) * 144; \
    _Pragma("unroll") \
    for (int d = 0; d < 6; ++d) { \
        qa[d] += (TK) * wr_[d]; \
        ka[d] += (TK) * wr_[48 + d]; \
        va[d] += (TK) * wr_[96 + d]; \
    } }

#define FF1_STEP(TK, ROW) { \
    const float* wr_ = wb + (ROW) * 192; \
    _Pragma("unroll") \
    for (int j = 0; j < 24; ++j) ha[j] += (TK) * wr_[j]; \
    }

__global__ __launch_bounds__(64, 3) void ka6_transformer(
    const float* __restrict__ x,
    const float* __restrict__ qkv_w, const float* __restrict__ qkv_b,
    const float* __restrict__ proj_w, const float* __restrict__ proj_b,
    const float* __restrict__ ff1_w, const float* __restrict__ ff1_b,
    const float* __restrict__ ff2_w, const float* __restrict__ ff2_b,
    float* __restrict__ t_out)
{
    __shared__ float tl[64 * LKS];     // per-lane token row (48 data + 1 pad)
    const int lane = threadIdx.x;

    // bijective XCD swizzle (grid not divisible by 8): chunked assignment
    const int nb  = gridDim.x;
    const int q8  = nb >> 3, r8 = nb & 7;
    const int xcd = blockIdx.x & 7, idx = blockIdx.x >> 3;
    const int wg  = (xcd < r8) ? xcd * (q8 + 1) + idx
                               : r8 * (q8 + 1) + (xcd - r8) * q8 + idx;

    const int s = lane / 10;
    const int c = lane - s * 10;                 // seq position 0..9
    const int g = wg * 6 + s;                    // global pixel (sequence) id
    const bool act = (lane < 60) && (g < 32768);
    const int b   = g >> 12;                     // batch image
    const int pix = g & 4095;

    float* tr = tl + lane * LKS;

    if (act) {
        const float* xp = x + ((size_t)(b * 480 + c * 48)) * 4096 + pix;
        #pragma unroll
        for (int f = 0; f < 48; ++f) tr[f] = xp[(size_t)f * 4096];
    } else {
        #pragma unroll
        for (int f = 0; f < 48; ++f) tr[f] = 0.f;
    }

    const float scale = 0.4082482904638631f;     // 6^-0.5
    const float NEG = -3.4e38f;

    for (int l = 0; l < 2; ++l) {
        const float* qw  = qkv_w + l * 6912;
        const float* qb  = qkv_b + l * 144;
        const float* pw  = proj_w + l * 2304;
        const float* pb  = proj_b + l * 48;
        const float* f1w = ff1_w + l * 9216;
        const float* f1b = ff1_b + l * 192;
        const float* f2w = ff2_w + l * 9216;
        const float* f2b = ff2_b + l * 48;

        float pacc[48];
        #pragma unroll
        for (int o = 0; o < 48; ++o) pacc[o] = 0.f;

        for (int h = 0; h < 8; ++h) {
            float qa[6], ka[6], va[6];
            #pragma unroll
            for (int d = 0; d < 6; ++d) { qa[d] = 0.f; ka[d] = 0.f; va[d] = 0.f; }

            // qkv GEMV in 3 blocks of 16 k: hoisted b128 t reads, then
            // a pure s_load+FMA body (no lgkmcnt mixing inside)
            for (int kb = 0; kb < 3; ++kb) {
                const float* trb = tr + kb * 16;
                float4 t0 = *(const float4*)(trb);
                float4 t1 = *(const float4*)(trb + 4);
                float4 t2 = *(const float4*)(trb + 8);
                float4 t3 = *(const float4*)(trb + 12);
                const float* wb = qw + (kb * 16) * 144 + h * 6;
                QKV_STEP(t0.x, 0)  QKV_STEP(t0.y, 1)  QKV_STEP(t0.z, 2)  QKV_STEP(t0.w, 3)
                QKV_STEP(t1.x, 4)  QKV_STEP(t1.y, 5)  QKV_STEP(t1.z, 6)  QKV_STEP(t1.w, 7)
                QKV_STEP(t2.x, 8)  QKV_STEP(t2.y, 9)  QKV_STEP(t2.z, 10) QKV_STEP(t2.w, 11)
                QKV_STEP(t3.x, 12) QKV_STEP(t3.y, 13) QKV_STEP(t3.z, 14) QKV_STEP(t3.w, 15)
            }
            #pragma unroll
            for (int d = 0; d < 6; ++d) {
                qa[d] += qb[h * 6 + d];
                ka[d] += qb[48 + h * 6 + d];
                va[d] += qb[96 + h * 6 + d];
            }

            float qm[6], qp[6], vm[6], vp[6];
            #pragma unroll
            for (int d = 0; d < 6; ++d) {
                qm[d] = __shfl_up(qa[d], 1);
                qp[d] = __shfl_down(qa[d], 1);
                vm[d] = __shfl_up(va[d], 1);
                vp[d] = __shfl_down(va[d], 1);
            }
            float s0 = 0.f, sm = 0.f, sp = 0.f;
            #pragma unroll
            for (int d = 0; d < 6; ++d) {
                s0 += ka[d] * qa[d];
                sm += ka[d] * qm[d];
                sp += ka[d] * qp[d];
            }
            s0 *= scale; sm *= scale; sp *= scale;
            if (c == 0) sm = NEG;
            if (c == 9) sp = NEG;
            const float mx = fmaxf(s0, fmaxf(sm, sp));
            const float em = expf(sm - mx), e0 = expf(s0 - mx), ep = expf(sp - mx);
            const float inv = 1.0f / (em + e0 + ep);

            #pragma unroll
            for (int d = 0; d < 6; ++d) {
                const float ov = (em * vm[d] + e0 * va[d] + ep * vp[d]) * inv;
                const float* wr = pw + (h * 6 + d) * 48;
                #pragma unroll
                for (int o = 0; o < 48; ++o) pacc[o] += ov * wr[o];
            }
        }
        #pragma unroll
        for (int f = 0; f < 48; ++f) tr[f] += pacc[f] + pb[f];

        float facc[48];
        #pragma unroll
        for (int o = 0; o < 48; ++o) facc[o] = 0.f;

        for (int cc = 0; cc < 8; ++cc) {
            float ha[24];
            #pragma unroll
            for (int j = 0; j < 24; ++j) ha[j] = 0.f;

            // ff1 GEMV in 3 blocks of 16 k: hoisted b128 t reads
            for (int kb = 0; kb < 3; ++kb) {
                const float* trb = tr + kb * 16;
                float4 t0 = *(const float4*)(trb);
                float4 t1 = *(const float4*)(trb + 4);
                float4 t2 = *(const float4*)(trb + 8);
                float4 t3 = *(const float4*)(trb + 12);
                const float* wb = f1w + (kb * 16) * 192 + cc * 24;
                FF1_STEP(t0.x, 0)  FF1_STEP(t0.y, 1)  FF1_STEP(t0.z, 2)  FF1_STEP(t0.w, 3)
                FF1_STEP(t1.x, 4)  FF1_STEP(t1.y, 5)  FF1_STEP(t1.z, 6)  FF1_STEP(t1.w, 7)
                FF1_STEP(t2.x, 8)  FF1_STEP(t2.y, 9)  FF1_STEP(t2.z, 10) FF1_STEP(t2.w, 11)
                FF1_STEP(t3.x, 12) FF1_STEP(t3.y, 13) FF1_STEP(t3.z, 14) FF1_STEP(t3.w, 15)
            }
            #pragma unroll
            for (int j = 0; j < 24; ++j) {
                float v = ha[j] + f1b[cc * 24 + j];
                ha[j] = 0.5f * v * (1.f + erff(v * 0.70710678118654752f));
            }
            #pragma unroll
            for (int j = 0; j < 24; ++j) {
                const float hj = ha[j];
                const float* wr = f2w + (cc * 24 + j) * 48;
                #pragma unroll
                for (int o = 0; o < 48; ++o) facc[o] += hj * wr[o];
            }
        }
        #pragma unroll
        for (int f = 0; f < 48; ++f) tr[f] += facc[f] + f2b[f];
    }

    if (act) {
        float* dst = t_out + (size_t)g * 480 + c * 48;
        #pragma unroll
        for (int u = 0; u < 12; ++u) {
            float4 v;
            v.x = tr[u * 4]; v.y = tr[u * 4 + 1];
            v.z = tr[u * 4 + 2]; v.w = tr[u * 4 + 3];
            *(float4*)(dst + u * 4) = v;
        }
    }
}

// ---------------- Kernel B: depthwise 3x3 conv (SAME) + transpose to pixel-major ----------------
__global__ __launch_bounds__(THREADS) void kb_conv(
    const float* __restrict__ x, const float* __restrict__ t_in,
    const float* __restrict__ dw_w, const float* __restrict__ dw_b,
    float* __restrict__ z0)
{
    __shared__ float ct[100 * 97];     // 10x10 halo tile x 96 ch, stride 97 (bank pad)
    const int tid = threadIdx.x;
    const int blk = blockIdx.x;
    const int n = blk >> 6;            // image (b*10+c)
    const int tile = blk & 63;
    const int th0 = (tile >> 3) << 3;
    const int tw0 = (tile & 7) << 3;
    const int b = n / 10, c = n % 10;

    for (int idx = tid; idx < 4800; idx += THREADS) {
        int f = idx / 100, p = idx % 100;
        int py = p / 10, px = p % 10;
        int gh = th0 + py - 1, gw = tw0 + px - 1;
        float v = 0.f;
        if ((unsigned)gh < 64u && (unsigned)gw < 64u)
            v = x[((size_t)n * 48 + f) * 4096 + gh * 64 + gw];
        ct[p * 97 + f] = v;
    }
    for (int idx = tid; idx < 4800; idx += THREADS) {
        int p = idx / 48, f = idx % 48;
        int py = p / 10, px = p % 10;
        int gh = th0 + py - 1, gw = tw0 + px - 1;
        float v = 0.f;
        if ((unsigned)gh < 64u && (unsigned)gw < 64u)
            v = t_in[(size_t)(b * 4096 + gh * 64 + gw) * 480 + c * 48 + f];
        ct[p * 97 + 48 + f] = v;
    }
    __syncthreads();

    #pragma unroll 4
    for (int it = 0; it < 24; ++it) {
        int oidx = tid + it * THREADS;   // 24*256 == 6144 == 64px * 96ch
        int pxl = oidx / 96, ch = oidx % 96;
        int py = pxl >> 3, pxx = pxl & 7;
        const float* wp = dw_w + ch * 9;
        float acc = dw_b[ch];
        #pragma unroll
        for (int dy = 0; dy < 3; ++dy)
            #pragma unroll
            for (int dx = 0; dx < 3; ++dx)
                acc += ct[((py + dy) * 10 + pxx + dx) * 97 + ch] * wp[dy * 3 + dx];
        z0[((size_t)n * 4096 + (th0 + py) * 64 + (tw0 + pxx)) * 96 + ch] = acc;
    }
}

// ---------------- Kernel C (v8, round-10 verified): lane = pixel, wave = j-slice ----------------
#define PBS 52

__global__ __launch_bounds__(THREADS, 4) void kc8_mlp(
    const float* __restrict__ x, const float* __restrict__ t_in,
    const float* __restrict__ z0,
    const float* __restrict__ ln_g, const float* __restrict__ ln_b,
    const float* __restrict__ pw1_w, const float* __restrict__ pw1_b,
    const float* __restrict__ pw2_w, const float* __restrict__ pw2_b,
    const float* __restrict__ sc_b,
    float* __restrict__ out)
{
    __shared__ float smem[3 * 64 * PBS];  // 9984 floats = 39.9KB union
    float* zb   = smem;                   // phase 1: z rows (64 x stride 100 = 6400)
    float* pbuf = smem;                   // phase 2: partials (3 x 64 x PBS)
    const int tid  = threadIdx.x;
    const int lane = tid & 63;
    const int w    = __builtin_amdgcn_readfirstlane(tid >> 6);  // SGPR wave id
    const int blk  = blockIdx.x;      // 5120
    const int n    = blk >> 6;        // image 0..79
    const int hw0  = (blk & 63) << 6; // 64-pixel run
    const size_t pixbase = (size_t)n * 4096 + hw0;

    // ---- stage z0 (contiguous 6144 floats) ----
    for (int idx = tid; idx < 1536; idx += THREADS) {
        float4 v = *(const float4*)(z0 + pixbase * 96 + (size_t)idx * 4);
        int p = idx / 24, c0 = (idx % 24) * 4;
        *(float4*)(&zb[p * 100 + c0]) = v;
    }
    __syncthreads();

    // ---- LayerNorm in place: one lane per pixel ----
    if (tid < 64) {
        float* r = zb + tid * 100;
        float mu = 0.f;
        #pragma unroll
        for (int k = 0; k < 96; ++k) mu += r[k];
        mu *= (1.f / 96.f);
        float var = 0.f;
        #pragma unroll
        for (int k = 0; k < 96; ++k) { float d = r[k] - mu; var += d * d; }
        var *= (1.f / 96.f);
        float rs = rsqrtf(var + 1e-6f);
        #pragma unroll
        for (int k = 0; k < 96; ++k) r[k] = (r[k] - mu) * rs * ln_g[k] + ln_b[k];
    }
    __syncthreads();

    // ---- per-wave partial: j in [96w, 96w+96), 4 sub-chunks of 24 ----
    float facc[48];
    #pragma unroll
    for (int o = 0; o < 48; ++o) facc[o] = (w == 0) ? pw2_b[o] : 0.f;

    const int jbase = w * 96;
    for (int sc4 = 0; sc4 < 4; ++sc4) {
        const int j0 = jbase + sc4 * 24;    // SGPR (w uniform, sc4 loop counter)
        float ha[24];
        #pragma unroll
        for (int j = 0; j < 24; ++j) ha[j] = 0.f;

        for (int k0 = 0; k0 < 96; k0 += 4) {
            float4 zv = *(const float4*)(&zb[lane * 100 + k0]);   // ds_read_b128
            {
                const float e = zv.x;
                const float* wr = pw1_w + (k0 + 0) * 384 + j0;    // s_load
                #pragma unroll
                for (int j = 0; j < 24; ++j) ha[j] += e * wr[j];
            }
            {
                const float e = zv.y;
                const float* wr = pw1_w + (k0 + 1) * 384 + j0;
                #pragma unroll
                for (int j = 0; j < 24; ++j) ha[j] += e * wr[j];
            }
            {
                const float e = zv.z;
                const float* wr = pw1_w + (k0 + 2) * 384 + j0;
                #pragma unroll
                for (int j = 0; j < 24; ++j) ha[j] += e * wr[j];
            }
            {
                const float e = zv.w;
                const float* wr = pw1_w + (k0 + 3) * 384 + j0;
                #pragma unroll
                for (int j = 0; j < 24; ++j) ha[j] += e * wr[j];
            }
        }
        #pragma unroll
        for (int j = 0; j < 24; ++j) {
            float v = ha[j] + pw1_b[j0 + j];
            ha[j] = 0.5f * v * (1.f + erff(v * 0.70710678118654752f));
        }
        #pragma unroll
        for (int j = 0; j < 24; ++j) {
            const float hj = ha[j];
            const float* wr = pw2_w + (j0 + j) * 48;              // s_load
            #pragma unroll
            for (int o = 0; o < 48; ++o) facc[o] += hj * wr[o];
        }
    }

    // ---- shortcut slice: wave w handles cat k in [24w, 24w+24) ----
    if (w < 2) {
        // x half (planar): k = 24w + i
        const float* xp = x + ((size_t)(n * 48 + w * 24)) * 4096 + hw0 + lane;
        #pragma unroll
        for (int i = 0; i < 24; ++i) {
            const float e = xp[(size_t)i * 4096];
            const float* wr = g_scwT + (w * 24 + i) * 48;         // s_load
            #pragma unroll
            for (int o = 0; o < 48; ++o) facc[o] += e * wr[o];
        }
    } else {
        // t half (pixel-major): k = 48 + 24(w-2) + u
        const float* tp = t_in + ((size_t)((n / 10) * 4096 + hw0 + lane)) * 480
                        + (n % 10) * 48 + (w - 2) * 24;
        #pragma unroll
        for (int u = 0; u < 6; ++u) {
            float4 v = *(const float4*)(tp + u * 4);
            const int kb = 48 + (w - 2) * 24 + u * 4;
            const float* w0p = g_scwT + (kb + 0) * 48;
            const float* w1p = g_scwT + (kb + 1) * 48;
            const float* w2p = g_scwT + (kb + 2) * 48;
            const float* w3p = g_scwT + (kb + 3) * 48;
            #pragma unroll
            for (int o = 0; o < 48; ++o) facc[o] += v.x * w0p[o];
            #pragma unroll
            for (int o = 0; o < 48; ++o) facc[o] += v.y * w1p[o];
            #pragma unroll
            for (int o = 0; o < 48; ++o) facc[o] += v.z * w2p[o];
            #pragma unroll
            for (int o = 0; o < 48; ++o) facc[o] += v.w * w3p[o];
        }
    }

    // ---- reduce partials (pbuf aliases zb: barrier before overwrite) ----
    __syncthreads();
    if (w > 0) {
        float* pb = pbuf + (w - 1) * (64 * PBS) + lane * PBS;
        #pragma unroll
        for (int o = 0; o < 48; ++o) pb[o] = facc[o];
    }
    __syncthreads();
    if (w == 0) {
        const float* p1 = pbuf + lane * PBS;
        const float* p2 = pbuf + (64 * PBS) + lane * PBS;
        const float* p3 = pbuf + 2 * (64 * PBS) + lane * PBS;
        #pragma unroll
        for (int o = 0; o < 48; ++o) facc[o] += p1[o];
        #pragma unroll
        for (int o = 0; o < 48; ++o) facc[o] += p2[o];
        #pragma unroll
        for (int o = 0; o < 48; ++o) facc[o] += p3[o];

        float* op = out + (size_t)n * 48 * 4096 + hw0 + lane;
        #pragma unroll
        for (int f = 0; f < 48; ++f)
            op[(size_t)f * 4096] = facc[f] + sc_b[f];
    }
}

extern "C" void kernel_launch(void* const* d_in, const int* in_sizes, int n_in,
                              void* d_out, int out_size, void* d_ws, size_t ws_size,
                              hipStream_t stream) {
    const float* x      = (const float*)d_in[0];
    const float* qkv_w  = (const float*)d_in[1];
    const float* qkv_b  = (const float*)d_in[2];
    const float* proj_w = (const float*)d_in[3];
    const float* proj_b = (const float*)d_in[4];
    const float* ff1_w  = (const float*)d_in[5];
    const float* ff1_b  = (const float*)d_in[6];
    const float* ff2_w  = (const float*)d_in[7];
    const float* ff2_b  = (const float*)d_in[8];
    const float* dw_w   = (const float*)d_in[9];
    const float* dw_b   = (const float*)d_in[10];
    const float* ln_g   = (const float*)d_in[11];
    const float* ln_b   = (const float*)d_in[12];
    const float* pw1_w  = (const float*)d_in[13];
    const float* pw1_b  = (const float*)d_in[14];
    const float* pw2_w  = (const float*)d_in[15];
    const float* pw2_b  = (const float*)d_in[16];
    const float* sc_w   = (const float*)d_in[17];
    const float* sc_b   = (const float*)d_in[18];
    float* out = (float*)d_out;

    // workspace: t_final (B*H*W,10,48) = 15,728,640 f ; z0 (80*4096,96) = 31,457,280 f
    float* t_out = (float*)d_ws;
    float* z0    = t_out + 15728640ull;

    kt_transpose<<<18, 256, 0, stream>>>(sc_w);
    ka6_transformer<<<5462, 64, 0, stream>>>(x, qkv_w, qkv_b, proj_w, proj_b,
                                             ff1_w, ff1_b, ff2_w, ff2_b, t_out);
    kb_conv<<<5120, THREADS, 0, stream>>>(x, t_out, dw_w, dw_b, z0);
    kc8_mlp<<<5120, THREADS, 0, stream>>>(x, t_out, z0, ln_g, ln_b,
                                          pw1_w, pw1_b, pw2_w, pw2_b, sc_b, out);
}

// Round 15
// 1797.859 us; speedup vs baseline: 1.3907x; 1.0802x over previous
//
#include <hip/hip_runtime.h>
#include <math.h>

#define THREADS 256

// Dims: B=8, C(seq)=10, F(dim)=48, H=W=64, HEADS=8, hd=6, MLP=192
// Stage2: NI=80 images, CH=96, PW=384, OUTF=48

// transposed shortcut weights [96][48], filled by kt_transpose each launch
__device__ float g_scwT[96 * 48];

// ---------------- Kernel T: transpose sc_w (48x96 -> 96x48), one-off ----------------
__global__ void kt_transpose(const float* __restrict__ sc_w) {
    int i = threadIdx.x + blockIdx.x * 256;
    if (i < 48 * 96) {
        int o = i / 96, k = i % 96;
        g_scwT[k * 48 + o] = sc_w[o * 96 + k];
    }
}

// ---------------- Kernel A (v2, round-10 verified 880us): lane = token ----------------
// One wave per block; 6 sequences per wave: lane = s*10 + c. t row per lane in
// LDS (stride 49 -> 2 lanes/bank, free). Weights wave-uniform -> s_load.
// Attention in registers via shfl +-1. Rolled k-loops (full unroll blows I$:
// round-11; 16-step macro bodies add VALU: round-14; phase-locked barriers
// drain lgkmcnt: round-13; contiguous reorder defeats prefetch: round-12 --
// this exact form is the verified local optimum).
#define LKS 49

__global__ __launch_bounds__(64, 3) void ka2_transformer(
    const float* __restrict__ x,
    const float* __restrict__ qkv_w, const float* __restrict__ qkv_b,
    const float* __restrict__ proj_w, const float* __restrict__ proj_b,
    const float* __restrict__ ff1_w, const float* __restrict__ ff1_b,
    const float* __restrict__ ff2_w, const float* __restrict__ ff2_b,
    float* __restrict__ t_out)
{
    __shared__ float tl[64 * LKS];     // per-lane token row (48 data + 1 pad)
    const int lane = threadIdx.x;

    // bijective XCD swizzle (grid not divisible by 8): chunked assignment
    const int nb  = gridDim.x;
    const int q8  = nb >> 3, r8 = nb & 7;
    const int xcd = blockIdx.x & 7, idx = blockIdx.x >> 3;
    const int wg  = (xcd < r8) ? xcd * (q8 + 1) + idx
                               : r8 * (q8 + 1) + (xcd - r8) * q8 + idx;

    const int s = lane / 10;
    const int c = lane - s * 10;                 // seq position 0..9
    const int g = wg * 6 + s;                    // global pixel (sequence) id
    const bool act = (lane < 60) && (g < 32768);
    const int b   = g >> 12;                     // batch image
    const int pix = g & 4095;

    float* tr = tl + lane * LKS;

    if (act) {
        const float* xp = x + ((size_t)(b * 480 + c * 48)) * 4096 + pix;
        #pragma unroll
        for (int f = 0; f < 48; ++f) tr[f] = xp[(size_t)f * 4096];
    } else {
        #pragma unroll
        for (int f = 0; f < 48; ++f) tr[f] = 0.f;
    }

    const float scale = 0.4082482904638631f;     // 6^-0.5
    const float NEG = -3.4e38f;

    for (int l = 0; l < 2; ++l) {
        const float* qw  = qkv_w + l * 6912;
        const float* qb  = qkv_b + l * 144;
        const float* pw  = proj_w + l * 2304;
        const float* pb  = proj_b + l * 48;
        const float* f1w = ff1_w + l * 9216;
        const float* f1b = ff1_b + l * 192;
        const float* f2w = ff2_w + l * 9216;
        const float* f2b = ff2_b + l * 48;

        float pacc[48];
        #pragma unroll
        for (int o = 0; o < 48; ++o) pacc[o] = 0.f;

        for (int h = 0; h < 8; ++h) {
            float qa[6], ka[6], va[6];
            #pragma unroll
            for (int d = 0; d < 6; ++d) { qa[d] = 0.f; ka[d] = 0.f; va[d] = 0.f; }

            for (int k = 0; k < 48; ++k) {
                const float tk = tr[k];
                const float* wr = qw + k * 144 + h * 6;
                #pragma unroll
                for (int d = 0; d < 6; ++d) {
                    qa[d] += tk * wr[d];
                    ka[d] += tk * wr[48 + d];
                    va[d] += tk * wr[96 + d];
                }
            }
            #pragma unroll
            for (int d = 0; d < 6; ++d) {
                qa[d] += qb[h * 6 + d];
                ka[d] += qb[48 + h * 6 + d];
                va[d] += qb[96 + h * 6 + d];
            }

            float qm[6], qp[6], vm[6], vp[6];
            #pragma unroll
            for (int d = 0; d < 6; ++d) {
                qm[d] = __shfl_up(qa[d], 1);
                qp[d] = __shfl_down(qa[d], 1);
                vm[d] = __shfl_up(va[d], 1);
                vp[d] = __shfl_down(va[d], 1);
            }
            float s0 = 0.f, sm = 0.f, sp = 0.f;
            #pragma unroll
            for (int d = 0; d < 6; ++d) {
                s0 += ka[d] * qa[d];
                sm += ka[d] * qm[d];
                sp += ka[d] * qp[d];
            }
            s0 *= scale; sm *= scale; sp *= scale;
            if (c == 0) sm = NEG;
            if (c == 9) sp = NEG;
            const float mx = fmaxf(s0, fmaxf(sm, sp));
            const float em = expf(sm - mx), e0 = expf(s0 - mx), ep = expf(sp - mx);
            const float inv = 1.0f / (em + e0 + ep);

            #pragma unroll
            for (int d = 0; d < 6; ++d) {
                const float ov = (em * vm[d] + e0 * va[d] + ep * vp[d]) * inv;
                const float* wr = pw + (h * 6 + d) * 48;
                #pragma unroll
                for (int o = 0; o < 48; ++o) pacc[o] += ov * wr[o];
            }
        }
        #pragma unroll
        for (int f = 0; f < 48; ++f) tr[f] += pacc[f] + pb[f];

        float facc[48];
        #pragma unroll
        for (int o = 0; o < 48; ++o) facc[o] = 0.f;

        for (int cc = 0; cc < 8; ++cc) {
            float ha[24];
            #pragma unroll
            for (int j = 0; j < 24; ++j) ha[j] = 0.f;

            for (int k = 0; k < 48; ++k) {
                const float tk = tr[k];
                const float* wr = f1w + k * 192 + cc * 24;
                #pragma unroll
                for (int j = 0; j < 24; ++j) ha[j] += tk * wr[j];
            }
            #pragma unroll
            for (int j = 0; j < 24; ++j) {
                float v = ha[j] + f1b[cc * 24 + j];
                ha[j] = 0.5f * v * (1.f + erff(v * 0.70710678118654752f));
            }
            #pragma unroll
            for (int j = 0; j < 24; ++j) {
                const float hj = ha[j];
                const float* wr = f2w + (cc * 24 + j) * 48;
                #pragma unroll
                for (int o = 0; o < 48; ++o) facc[o] += hj * wr[o];
            }
        }
        #pragma unroll
        for (int f = 0; f < 48; ++f) tr[f] += facc[f] + f2b[f];
    }

    if (act) {
        float* dst = t_out + (size_t)g * 480 + c * 48;
        #pragma unroll
        for (int u = 0; u < 12; ++u) {
            float4 v;
            v.x = tr[u * 4]; v.y = tr[u * 4 + 1];
            v.z = tr[u * 4 + 2]; v.w = tr[u * 4 + 3];
            *(float4*)(dst + u * 4) = v;
        }
    }
}

// ---------------- Kernel B: depthwise 3x3 conv (SAME) + transpose to pixel-major ----------------
__global__ __launch_bounds__(THREADS) void kb_conv(
    const float* __restrict__ x, const float* __restrict__ t_in,
    const float* __restrict__ dw_w, const float* __restrict__ dw_b,
    float* __restrict__ z0)
{
    __shared__ float ct[100 * 97];     // 10x10 halo tile x 96 ch, stride 97 (bank pad)
    const int tid = threadIdx.x;
    const int blk = blockIdx.x;
    const int n = blk >> 6;            // image (b*10+c)
    const int tile = blk & 63;
    const int th0 = (tile >> 3) << 3;
    const int tw0 = (tile & 7) << 3;
    const int b = n / 10, c = n % 10;

    for (int idx = tid; idx < 4800; idx += THREADS) {
        int f = idx / 100, p = idx % 100;
        int py = p / 10, px = p % 10;
        int gh = th0 + py - 1, gw = tw0 + px - 1;
        float v = 0.f;
        if ((unsigned)gh < 64u && (unsigned)gw < 64u)
            v = x[((size_t)n * 48 + f) * 4096 + gh * 64 + gw];
        ct[p * 97 + f] = v;
    }
    for (int idx = tid; idx < 4800; idx += THREADS) {
        int p = idx / 48, f = idx % 48;
        int py = p / 10, px = p % 10;
        int gh = th0 + py - 1, gw = tw0 + px - 1;
        float v = 0.f;
        if ((unsigned)gh < 64u && (unsigned)gw < 64u)
            v = t_in[(size_t)(b * 4096 + gh * 64 + gw) * 480 + c * 48 + f];
        ct[p * 97 + 48 + f] = v;
    }
    __syncthreads();

    #pragma unroll 4
    for (int it = 0; it < 24; ++it) {
        int oidx = tid + it * THREADS;   // 24*256 == 6144 == 64px * 96ch
        int pxl = oidx / 96, ch = oidx % 96;
        int py = pxl >> 3, pxx = pxl & 7;
        const float* wp = dw_w + ch * 9;
        float acc = dw_b[ch];
        #pragma unroll
        for (int dy = 0; dy < 3; ++dy)
            #pragma unroll
            for (int dx = 0; dx < 3; ++dx)
                acc += ct[((py + dy) * 10 + pxx + dx) * 97 + ch] * wp[dy * 3 + dx];
        z0[((size_t)n * 4096 + (th0 + py) * 64 + (tw0 + pxx)) * 96 + ch] = acc;
    }
}

// ---------------- Kernel C (v8, round-10 verified): lane = pixel, wave = j-slice ----------------
#define PBS 52

__global__ __launch_bounds__(THREADS, 4) void kc8_mlp(
    const float* __restrict__ x, const float* __restrict__ t_in,
    const float* __restrict__ z0,
    const float* __restrict__ ln_g, const float* __restrict__ ln_b,
    const float* __restrict__ pw1_w, const float* __restrict__ pw1_b,
    const float* __restrict__ pw2_w, const float* __restrict__ pw2_b,
    const float* __restrict__ sc_b,
    float* __restrict__ out)
{
    __shared__ float smem[3 * 64 * PBS];  // 9984 floats = 39.9KB union
    float* zb   = smem;                   // phase 1: z rows (64 x stride 100 = 6400)
    float* pbuf = smem;                   // phase 2: partials (3 x 64 x PBS)
    const int tid  = threadIdx.x;
    const int lane = tid & 63;
    const int w    = __builtin_amdgcn_readfirstlane(tid >> 6);  // SGPR wave id
    const int blk  = blockIdx.x;      // 5120
    const int n    = blk >> 6;        // image 0..79
    const int hw0  = (blk & 63) << 6; // 64-pixel run
    const size_t pixbase = (size_t)n * 4096 + hw0;

    // ---- stage z0 (contiguous 6144 floats) ----
    for (int idx = tid; idx < 1536; idx += THREADS) {
        float4 v = *(const float4*)(z0 + pixbase * 96 + (size_t)idx * 4);
        int p = idx / 24, c0 = (idx % 24) * 4;
        *(float4*)(&zb[p * 100 + c0]) = v;
    }
    __syncthreads();

    // ---- LayerNorm in place: one lane per pixel ----
    if (tid < 64) {
        float* r = zb + tid * 100;
        float mu = 0.f;
        #pragma unroll
        for (int k = 0; k < 96; ++k) mu += r[k];
        mu *= (1.f / 96.f);
        float var = 0.f;
        #pragma unroll
        for (int k = 0; k < 96; ++k) { float d = r[k] - mu; var += d * d; }
        var *= (1.f / 96.f);
        float rs = rsqrtf(var + 1e-6f);
        #pragma unroll
        for (int k = 0; k < 96; ++k) r[k] = (r[k] - mu) * rs * ln_g[k] + ln_b[k];
    }
    __syncthreads();

    // ---- per-wave partial: j in [96w, 96w+96), 4 sub-chunks of 24 ----
    float facc[48];
    #pragma unroll
    for (int o = 0; o < 48; ++o) facc[o] = (w == 0) ? pw2_b[o] : 0.f;

    const int jbase = w * 96;
    for (int sc4 = 0; sc4 < 4; ++sc4) {
        const int j0 = jbase + sc4 * 24;    // SGPR (w uniform, sc4 loop counter)
        float ha[24];
        #pragma unroll
        for (int j = 0; j < 24; ++j) ha[j] = 0.f;

        for (int k0 = 0; k0 < 96; k0 += 4) {
            float4 zv = *(const float4*)(&zb[lane * 100 + k0]);   // ds_read_b128
            {
                const float e = zv.x;
                const float* wr = pw1_w + (k0 + 0) * 384 + j0;    // s_load
                #pragma unroll
                for (int j = 0; j < 24; ++j) ha[j] += e * wr[j];
            }
            {
                const float e = zv.y;
                const float* wr = pw1_w + (k0 + 1) * 384 + j0;
                #pragma unroll
                for (int j = 0; j < 24; ++j) ha[j] += e * wr[j];
            }
            {
                const float e = zv.z;
                const float* wr = pw1_w + (k0 + 2) * 384 + j0;
                #pragma unroll
                for (int j = 0; j < 24; ++j) ha[j] += e * wr[j];
            }
            {
                const float e = zv.w;
                const float* wr = pw1_w + (k0 + 3) * 384 + j0;
                #pragma unroll
                for (int j = 0; j < 24; ++j) ha[j] += e * wr[j];
            }
        }
        #pragma unroll
        for (int j = 0; j < 24; ++j) {
            float v = ha[j] + pw1_b[j0 + j];
            ha[j] = 0.5f * v * (1.f + erff(v * 0.70710678118654752f));
        }
        #pragma unroll
        for (int j = 0; j < 24; ++j) {
            const float hj = ha[j];
            const float* wr = pw2_w + (j0 + j) * 48;              // s_load
            #pragma unroll
            for (int o = 0; o < 48; ++o) facc[o] += hj * wr[o];
        }
    }

    // ---- shortcut slice: wave w handles cat k in [24w, 24w+24) ----
    if (w < 2) {
        // x half (planar): k = 24w + i
        const float* xp = x + ((size_t)(n * 48 + w * 24)) * 4096 + hw0 + lane;
        #pragma unroll
        for (int i = 0; i < 24; ++i) {
            const float e = xp[(size_t)i * 4096];
            const float* wr = g_scwT + (w * 24 + i) * 48;         // s_load
            #pragma unroll
            for (int o = 0; o < 48; ++o) facc[o] += e * wr[o];
        }
    } else {
        // t half (pixel-major): k = 48 + 24(w-2) + u
        const float* tp = t_in + ((size_t)((n / 10) * 4096 + hw0 + lane)) * 480
                        + (n % 10) * 48 + (w - 2) * 24;
        #pragma unroll
        for (int u = 0; u < 6; ++u) {
            float4 v = *(const float4*)(tp + u * 4);
            const int kb = 48 + (w - 2) * 24 + u * 4;
            const float* w0p = g_scwT + (kb + 0) * 48;
            const float* w1p = g_scwT + (kb + 1) * 48;
            const float* w2p = g_scwT + (kb + 2) * 48;
            const float* w3p = g_scwT + (kb + 3) * 48;
            #pragma unroll
            for (int o = 0; o < 48; ++o) facc[o] += v.x * w0p[o];
            #pragma unroll
            for (int o = 0; o < 48; ++o) facc[o] += v.y * w1p[o];
            #pragma unroll
            for (int o = 0; o < 48; ++o) facc[o] += v.z * w2p[o];
            #pragma unroll
            for (int o = 0; o < 48; ++o) facc[o] += v.w * w3p[o];
        }
    }

    // ---- reduce partials (pbuf aliases zb: barrier before overwrite) ----
    __syncthreads();
    if (w > 0) {
        float* pb = pbuf + (w - 1) * (64 * PBS) + lane * PBS;
        #pragma unroll
        for (int o = 0; o < 48; ++o) pb[o] = facc[o];
    }
    __syncthreads();
    if (w == 0) {
        const float* p1 = pbuf + lane * PBS;
        const float* p2 = pbuf + (64 * PBS) + lane * PBS;
        const float* p3 = pbuf + 2 * (64 * PBS) + lane * PBS;
        #pragma unroll
        for (int o = 0; o < 48; ++o) facc[o] += p1[o];
        #pragma unroll
        for (int o = 0; o < 48; ++o) facc[o] += p2[o];
        #pragma unroll
        for (int o = 0; o < 48; ++o) facc[o] += p3[o];

        float* op = out + (size_t)n * 48 * 4096 + hw0 + lane;
        #pragma unroll
        for (int f = 0; f < 48; ++f)
            op[(size_t)f * 4096] = facc[f] + sc_b[f];
    }
}

extern "C" void kernel_launch(void* const* d_in, const int* in_sizes, int n_in,
                              void* d_out, int out_size, void* d_ws, size_t ws_size,
                              hipStream_t stream) {
    const float* x      = (const float*)d_in[0];
    const float* qkv_w  = (const float*)d_in[1];
    const float* qkv_b  = (const float*)d_in[2];
    const float* proj_w = (const float*)d_in[3];
    const float* proj_b = (const float*)d_in[4];
    const float* ff1_w  = (const float*)d_in[5];
    const float* ff1_b  = (const float*)d_in[6];
    const float* ff2_w  = (const float*)d_in[7];
    const float* ff2_b  = (const float*)d_in[8];
    const float* dw_w   = (const float*)d_in[9];
    const float* dw_b   = (const float*)d_in[10];
    const float* ln_g   = (const float*)d_in[11];
    const float* ln_b   = (const float*)d_in[12];
    const float* pw1_w  = (const float*)d_in[13];
    const float* pw1_b  = (const float*)d_in[14];
    const float* pw2_w  = (const float*)d_in[15];
    const float* pw2_b  = (const float*)d_in[16];
    const float* sc_w   = (const float*)d_in[17];
    const float* sc_b   = (const float*)d_in[18];
    float* out = (float*)d_out;

    // workspace: t_final (B*H*W,10,48) = 15,728,640 f ; z0 (80*4096,96) = 31,457,280 f
    float* t_out = (float*)d_ws;
    float* z0    = t_out + 15728640ull;

    kt_transpose<<<18, 256, 0, stream>>>(sc_w);
    ka2_transformer<<<5462, 64, 0, stream>>>(x, qkv_w, qkv_b, proj_w, proj_b,
                                             ff1_w, ff1_b, ff2_w, ff2_b, t_out);
    kb_conv<<<5120, THREADS, 0, stream>>>(x, t_out, dw_w, dw_b, z0);
    kc8_mlp<<<5120, THREADS, 0, stream>>>(x, t_out, z0, ln_g, ln_b,
                                          pw1_w, pw1_b, pw2_w, pw2_b, sc_b, out);
}